// Round 6
// baseline (435.574 us; speedup 1.0000x reference)
//
#include <hip/hip_runtime.h>
#include <hip/hip_bf16.h>

typedef unsigned short u16;
typedef float  f32x4  __attribute__((ext_vector_type(4)));
typedef __bf16 bf16x8 __attribute__((ext_vector_type(8)));
typedef unsigned short u16x8 __attribute__((ext_vector_type(8)));
typedef unsigned short u16x4 __attribute__((ext_vector_type(4)));

__device__ __forceinline__ u16 f2bfu(float f) {
    __hip_bfloat16 h = __float2bfloat16(f);
    return __builtin_bit_cast(unsigned short, h);
}

constexpr int kHW = 196;   // 14*14
constexpr int kKC = 25;    // ceil(196/8)  k-chunks (8 k rows per tile)
constexpr int kLC = 49;    // 196/4        l-chunks (4 l rows per tile)
constexpr int kChunks = kKC * kLC;  // 1225 per batch

// ---------------- fp32 64x64 tile transpose ----------------
__global__ void k_tr_f32(const float* __restrict__ in, float* __restrict__ out,
                         int R, int Ccols) {
    __shared__ float t[64][65];
    int c0 = blockIdx.x * 64, r0 = blockIdx.y * 64;
    int lc = threadIdx.x & 63, lg = threadIdx.x >> 6;
#pragma unroll
    for (int rr = 0; rr < 16; ++rr) {
        int r = lg * 16 + rr;
        t[r][lc] = in[(r0 + r) * Ccols + c0 + lc];
    }
    __syncthreads();
#pragma unroll
    for (int rr = 0; rr < 16; ++rr) {
        int r = lg * 16 + rr;
        out[(c0 + r) * R + r0 + lc] = t[lc][r];
    }
}

// ---------------- fp32 -> bf16 transpose ----------------
__global__ void k_tr_bf16(const float* __restrict__ in, u16* __restrict__ out,
                          int R, int Ccols) {
    __shared__ float t[64][65];
    int c0 = blockIdx.x * 64, r0 = blockIdx.y * 64;
    int lc = threadIdx.x & 63, lg = threadIdx.x >> 6;
#pragma unroll
    for (int rr = 0; rr < 16; ++rr) {
        int r = lg * 16 + rr;
        t[r][lc] = in[(r0 + r) * Ccols + c0 + lc];
    }
    __syncthreads();
#pragma unroll
    for (int rr = 0; rr < 16; ++rr) {
        int r = lg * 16 + rr;
        out[(c0 + r) * R + r0 + lc] = f2bfu(t[lc][r]);
    }
}

// ---------------- fused xf + al/ak: grid (25, 8), 512 thr ----------------
__global__ __launch_bounds__(512)
void k_xa(const float* __restrict__ im, const float* __restrict__ pwT,
          const float* __restrict__ pb, const float* __restrict__ w1,
          float* __restrict__ al, float* __restrict__ ak) {
    __shared__ float sm[512 * 8];
    __shared__ float smx[256 * 8];
    const int tid = threadIdx.x;
    const int b = blockIdx.y;
    const int p0 = blockIdx.x * 8;
#pragma unroll
    for (int it = 0; it < 8; ++it) {
        int idx = it * 512 + tid;
        int i = idx >> 3, pi = idx & 7;
        int p = p0 + pi;
        sm[idx] = (p < kHW) ? im[(b * 512 + i) * kHW + p] : 0.f;
    }
    __syncthreads();
    const int c = tid & 255;
    const int half = tid >> 8;
    float acc[8] = {};
    {
        const int ibase = half * 256;
        for (int k = 0; k < 256; ++k) {
            int i = ibase + k;
            float w = pwT[(i << 8) + c];
            f32x4 x0 = *(const f32x4*)&sm[i * 8];
            f32x4 x1 = *(const f32x4*)&sm[i * 8 + 4];
#pragma unroll
            for (int j = 0; j < 4; ++j) { acc[j] += x0[j] * w; acc[4 + j] += x1[j] * w; }
        }
    }
    __syncthreads();
    if (half) {
#pragma unroll
        for (int pi = 0; pi < 8; ++pi) sm[c * 8 + pi] = acc[pi];
    }
    __syncthreads();
    if (!half) {
        float bias = pb[c];
#pragma unroll
        for (int pi = 0; pi < 8; ++pi) smx[c * 8 + pi] = acc[pi] + sm[c * 8 + pi] + bias;
    }
    __syncthreads();
    float a2[8] = {};
    const float* wb = w1 + half * 256 * 256;
    for (int k = 0; k < 256; ++k) {
        float w = wb[(k << 8) + c];
        f32x4 x0 = *(const f32x4*)&smx[k * 8];
        f32x4 x1 = *(const f32x4*)&smx[k * 8 + 4];
#pragma unroll
        for (int j = 0; j < 4; ++j) { a2[j] += x0[j] * w; a2[4 + j] += x1[j] * w; }
    }
    float* dst = half ? ak : al;
#pragma unroll
    for (int pi = 0; pi < 8; ++pi) {
        int p = p0 + pi;
        if (p < kHW) dst[((b * kHW + p) << 8) + c] = a2[pi];
    }
}

// ---------------- main fused pair kernel v5: small tiles, high occupancy ----------------
// grid (49 lc, 25 kc, 8 b) = 9800 blocks, block 256 = 4 waves (wn = ch quarter).
// Tile: (8 k x 4 l) = 32 pairs x 256 ch. Wave tile: 64 ch x 32 pairs
// -> acc[4][2] f32x4 = 32 AGPR; total ~117 unified regs -> 4 blocks/CU.
// LDS 16 KB. Simple 2-barrier structure (compiler schedules K-loop well).
__global__ __launch_bounds__(256, 4)
void k_main5(const float* __restrict__ ak, const float* __restrict__ al,
             const float* __restrict__ b1, const u16* __restrict__ w2t,
             const float* __restrict__ b2, const u16* __restrict__ w3t,
             const float* __restrict__ b3, float* __restrict__ part) {
    __shared__ u16 smem[32 * 256];  // 16 KB: h1, then h2 in-place
    const int tid = threadIdx.x;
    const int lc = blockIdx.x, kc = blockIdx.y, b = blockIdx.z;
    const int k0 = kc * 8, l0 = lc * 4;

    // ---- stage h1 = relu(ak[k] + al[l] + b1) -> bf16 LDS [pair][ch], swizzled ----
#pragma unroll
    for (int it = 0; it < 4; ++it) {
        int chunk = it * 256 + tid;
        int row = chunk >> 5;   // 0..31 = (ki-k0)*4 + (li-l0)
        int cc = chunk & 31;    // 8-ch group
        int ki = k0 + (row >> 2); if (ki > 195) ki = 195;
        int li = l0 + (row & 3);
        const float* akp = ak + ((b * kHW + ki) << 8) + (cc << 3);
        const float* alp = al + ((b * kHW + li) << 8) + (cc << 3);
        const float* b1p = b1 + (cc << 3);
        f32x4 k0v = *(const f32x4*)akp;
        f32x4 k1v = *(const f32x4*)(akp + 4);
        f32x4 l0v = *(const f32x4*)alp;
        f32x4 l1v = *(const f32x4*)(alp + 4);
        f32x4 c0v = *(const f32x4*)b1p;
        f32x4 c1v = *(const f32x4*)(b1p + 4);
        u16x8 v;
#pragma unroll
        for (int j = 0; j < 4; ++j) {
            v[j]     = f2bfu(fmaxf(k0v[j] + l0v[j] + c0v[j], 0.f));
            v[4 + j] = f2bfu(fmaxf(k1v[j] + l1v[j] + c1v[j], 0.f));
        }
        int byte = (row << 9) + (cc << 4);
        byte ^= (row & 7) << 4;
        *(u16x8*)((char*)smem + byte) = v;
    }
    __syncthreads();

    const int lane = tid & 63;
    const int wn = tid >> 6;   // wave = ch quarter 0..3
    const int l15 = lane & 15;
    const int kg = lane >> 4;  // 0..3

    f32x4 acc[4][2];  // [fn ch-frag][fm pair-frag], reused for both GEMMs

    // ---- GEMM1: h2^T = w2 x h1^T ----
#pragma unroll
    for (int fn = 0; fn < 4; ++fn)
#pragma unroll
        for (int fm = 0; fm < 2; ++fm) acc[fn][fm] = f32x4{0.f, 0.f, 0.f, 0.f};
    for (int kk = 0; kk < 8; ++kk) {
        int kb = kk * 32 + kg * 8;
        bf16x8 hb[2];
#pragma unroll
        for (int fm = 0; fm < 2; ++fm) {
            int row = fm * 16 + l15;
            int byte = (row << 9) + (kb << 1);
            byte ^= (row & 7) << 4;
            hb[fm] = __builtin_bit_cast(bf16x8, *(const u16x8*)((const char*)smem + byte));
        }
#pragma unroll
        for (int fn = 0; fn < 4; ++fn) {
            bf16x8 aw = __builtin_bit_cast(
                bf16x8, *(const u16x8*)(w2t + ((wn * 64 + fn * 16 + l15) << 8) + kb));
#pragma unroll
            for (int fm = 0; fm < 2; ++fm)
                acc[fn][fm] = __builtin_amdgcn_mfma_f32_16x16x32_bf16(aw, hb[fm], acc[fn][fm], 0, 0, 0);
        }
    }
    __syncthreads();

    // ---- epilogue: h2 = relu(D1 + b2) -> bf16 LDS, packed 8B writes ----
#pragma unroll
    for (int fn = 0; fn < 4; ++fn) {
        f32x4 b2v = *(const f32x4*)(b2 + wn * 64 + fn * 16 + kg * 4);
#pragma unroll
        for (int fm = 0; fm < 2; ++fm) {
            int prow = fm * 16 + l15;
            u16x4 pv;
#pragma unroll
            for (int r = 0; r < 4; ++r)
                pv[r] = f2bfu(fmaxf(acc[fn][fm][r] + b2v[r], 0.f));
            int byte = (prow << 9) + ((wn * 64 + fn * 16 + kg * 4) << 1);
            byte ^= (prow & 7) << 4;
            *(u16x4*)((char*)smem + byte) = pv;
        }
    }
    __syncthreads();

    // ---- GEMM2: h3^T = w3 x h2^T ----
#pragma unroll
    for (int fn = 0; fn < 4; ++fn)
#pragma unroll
        for (int fm = 0; fm < 2; ++fm) acc[fn][fm] = f32x4{0.f, 0.f, 0.f, 0.f};
    for (int kk = 0; kk < 8; ++kk) {
        int kb = kk * 32 + kg * 8;
        bf16x8 hb[2];
#pragma unroll
        for (int fm = 0; fm < 2; ++fm) {
            int row = fm * 16 + l15;
            int byte = (row << 9) + (kb << 1);
            byte ^= (row & 7) << 4;
            hb[fm] = __builtin_bit_cast(bf16x8, *(const u16x8*)((const char*)smem + byte));
        }
#pragma unroll
        for (int fn = 0; fn < 4; ++fn) {
            bf16x8 aw = __builtin_bit_cast(
                bf16x8, *(const u16x8*)(w3t + ((wn * 64 + fn * 16 + l15) << 8) + kb));
#pragma unroll
            for (int fm = 0; fm < 2; ++fm)
                acc[fn][fm] = __builtin_amdgcn_mfma_f32_16x16x32_bf16(aw, hb[fm], acc[fn][fm], 0, 0, 0);
        }
    }

    // ---- masked col-sum + 16-lane reduce + direct store (each wave owns 64 ch) ----
    float s[4][4] = {};
#pragma unroll
    for (int fm = 0; fm < 2; ++fm) {
        int pr = fm * 16 + l15;
        int ki = k0 + (pr >> 2);
        float vm = (ki < kHW) ? 1.f : 0.f;
#pragma unroll
        for (int fn = 0; fn < 4; ++fn) {
            f32x4 b3v = *(const f32x4*)(b3 + wn * 64 + fn * 16 + kg * 4);
#pragma unroll
            for (int r = 0; r < 4; ++r)
                s[fn][r] += vm * fmaxf(acc[fn][fm][r] + b3v[r], 0.f);
        }
    }
#pragma unroll
    for (int fn = 0; fn < 4; ++fn)
#pragma unroll
        for (int r = 0; r < 4; ++r) {
            s[fn][r] += __shfl_xor(s[fn][r], 1);
            s[fn][r] += __shfl_xor(s[fn][r], 2);
            s[fn][r] += __shfl_xor(s[fn][r], 4);
            s[fn][r] += __shfl_xor(s[fn][r], 8);
        }
    if (l15 == 0) {
        int chunkid = (b * kKC + kc) * kLC + lc;
        float* pp = part + chunkid * 256 + wn * 64 + kg * 4;
#pragma unroll
        for (int fn = 0; fn < 4; ++fn)
            *(f32x4*)(pp + fn * 16) = f32x4{s[fn][0], s[fn][1], s[fn][2], s[fn][3]};
    }
}

// ---------------- final reduce over 1225 chunks per batch ----------------
__global__ __launch_bounds__(1024)
void k_reduce(const float* __restrict__ part, float* __restrict__ out) {
    __shared__ float red[4][256];
    int b = blockIdx.x;
    int c = threadIdx.x & 255;
    int stripe = threadIdx.x >> 8;
    const float* p = part + (b * kChunks) * 256 + c;
    float s = 0.f;
    for (int j = stripe; j < kChunks; j += 4) s += p[j * 256];
    red[stripe][c] = s;
    __syncthreads();
    if (threadIdx.x < 256)
        out[b * 256 + threadIdx.x] = red[0][threadIdx.x] + red[1][threadIdx.x] +
                                     red[2][threadIdx.x] + red[3][threadIdx.x];
}

extern "C" void kernel_launch(void* const* d_in, const int* in_sizes, int n_in,
                              void* d_out, int out_size, void* d_ws, size_t ws_size,
                              hipStream_t stream) {
    const float* im = (const float*)d_in[0];
    const float* pw = (const float*)d_in[3];
    const float* pb = (const float*)d_in[4];
    const float* w1 = (const float*)d_in[5];
    const float* b1 = (const float*)d_in[6];
    const float* w2 = (const float*)d_in[7];
    const float* b2 = (const float*)d_in[8];
    const float* w3 = (const float*)d_in[9];
    const float* b3 = (const float*)d_in[10];
    float* out = (float*)d_out;

    float* al  = (float*)d_ws;            // 8*196*256
    float* ak  = al + 8 * 196 * 256;
    float* pwT = ak + 8 * 196 * 256;      // [512][256]
    u16* w2t = (u16*)(pwT + 512 * 256);   // [256][256] bf16, [n][k]
    u16* w3t = w2t + 256 * 256;
    float* part = (float*)(w3t + 256 * 256);  // [8*1225][256] = 10.0 MB

    hipLaunchKernelGGL(k_tr_f32, dim3(8, 4), dim3(256), 0, stream, pw, pwT, 256, 512);
    hipLaunchKernelGGL(k_tr_bf16, dim3(4, 4), dim3(256), 0, stream, w2, w2t, 256, 256);
    hipLaunchKernelGGL(k_tr_bf16, dim3(4, 4), dim3(256), 0, stream, w3, w3t, 256, 256);
    hipLaunchKernelGGL(k_xa, dim3(25, 8), dim3(512), 0, stream, im, pwT, pb, w1, al, ak);
    hipLaunchKernelGGL(k_main5, dim3(kLC, kKC, 8), dim3(256), 0, stream,
                       ak, al, b1, w2t, b2, w3t, b3, part);
    hipLaunchKernelGGL(k_reduce, dim3(8), dim3(1024), 0, stream, part, out);
}

// Round 7
// 171.409 us; speedup vs baseline: 2.5411x; 2.5411x over previous
//
#include <hip/hip_runtime.h>
#include <hip/hip_bf16.h>

typedef unsigned short u16;
typedef float  f32x4  __attribute__((ext_vector_type(4)));
typedef __bf16 bf16x8 __attribute__((ext_vector_type(8)));
typedef unsigned short u16x8 __attribute__((ext_vector_type(8)));
typedef unsigned short u16x4 __attribute__((ext_vector_type(4)));

__device__ __forceinline__ u16 f2bfu(float f) {
    __hip_bfloat16 h = __float2bfloat16(f);
    return __builtin_bit_cast(unsigned short, h);
}

constexpr int kHW = 196;   // 14*14
constexpr int kKC = 25;    // ceil(196/8) k-chunks
constexpr int kLC = 25;    // ceil(196/8) l-chunks
constexpr int kChunks = kKC * kLC;  // 625 per batch

// ---------------- fp32 64x64 tile transpose ----------------
__global__ void k_tr_f32(const float* __restrict__ in, float* __restrict__ out,
                         int R, int Ccols) {
    __shared__ float t[64][65];
    int c0 = blockIdx.x * 64, r0 = blockIdx.y * 64;
    int lc = threadIdx.x & 63, lg = threadIdx.x >> 6;
#pragma unroll
    for (int rr = 0; rr < 16; ++rr) {
        int r = lg * 16 + rr;
        t[r][lc] = in[(r0 + r) * Ccols + c0 + lc];
    }
    __syncthreads();
#pragma unroll
    for (int rr = 0; rr < 16; ++rr) {
        int r = lg * 16 + rr;
        out[(c0 + r) * R + r0 + lc] = t[lc][r];
    }
}

// ---------------- weight interleave: in [k][n] fp32 -> out bf16 [kk][kg][n][k8] ----
// Fragment for MFMA lane: 8 consecutive k at (kk*32 + kg*8); lanes l15 consecutive n
// -> each 16-lane fragment load reads 256 CONTIGUOUS bytes (kills the 64-line gather).
__global__ void k_wint(const float* __restrict__ in, u16* __restrict__ out) {
    int n = threadIdx.x;   // 0..255
    int k = blockIdx.x;    // 0..255
    int kk = k >> 5, kg = (k >> 3) & 3, k8 = k & 7;
    out[(((((kk << 2) + kg) << 8) + n) << 3) + k8] = f2bfu(in[(k << 8) + n]);
}

// ---------------- fused xf + al/ak: grid (25, 8), 512 thr ----------------
__global__ __launch_bounds__(512)
void k_xa(const float* __restrict__ im, const float* __restrict__ pwT,
          const float* __restrict__ pb, const float* __restrict__ w1,
          float* __restrict__ al, float* __restrict__ ak) {
    __shared__ float sm[512 * 8];
    __shared__ float smx[256 * 8];
    const int tid = threadIdx.x;
    const int b = blockIdx.y;
    const int p0 = blockIdx.x * 8;
#pragma unroll
    for (int it = 0; it < 8; ++it) {
        int idx = it * 512 + tid;
        int i = idx >> 3, pi = idx & 7;
        int p = p0 + pi;
        sm[idx] = (p < kHW) ? im[(b * 512 + i) * kHW + p] : 0.f;
    }
    __syncthreads();
    const int c = tid & 255;
    const int half = tid >> 8;
    float acc[8] = {};
    {
        const int ibase = half * 256;
        for (int k = 0; k < 256; ++k) {
            int i = ibase + k;
            float w = pwT[(i << 8) + c];
            f32x4 x0 = *(const f32x4*)&sm[i * 8];
            f32x4 x1 = *(const f32x4*)&sm[i * 8 + 4];
#pragma unroll
            for (int j = 0; j < 4; ++j) { acc[j] += x0[j] * w; acc[4 + j] += x1[j] * w; }
        }
    }
    __syncthreads();
    if (half) {
#pragma unroll
        for (int pi = 0; pi < 8; ++pi) sm[c * 8 + pi] = acc[pi];
    }
    __syncthreads();
    if (!half) {
        float bias = pb[c];
#pragma unroll
        for (int pi = 0; pi < 8; ++pi) smx[c * 8 + pi] = acc[pi] + sm[c * 8 + pi] + bias;
    }
    __syncthreads();
    float a2[8] = {};
    const float* wb = w1 + half * 256 * 256;
    for (int k = 0; k < 256; ++k) {
        float w = wb[(k << 8) + c];
        f32x4 x0 = *(const f32x4*)&smx[k * 8];
        f32x4 x1 = *(const f32x4*)&smx[k * 8 + 4];
#pragma unroll
        for (int j = 0; j < 4; ++j) { a2[j] += x0[j] * w; a2[4 + j] += x1[j] * w; }
    }
    float* dst = half ? ak : al;
#pragma unroll
    for (int pi = 0; pi < 8; ++pi) {
        int p = p0 + pi;
        if (p < kHW) dst[((b * kHW + p) << 8) + c] = a2[pi];
    }
}

// ---------------- main fused pair kernel v6 = v3 + interleaved weight loads ----------
// grid (25 lc, 25 kc, 8 b) = 5000 blocks, block 256 (4 waves; wave = ch quarter).
// Tile: (8 k x 8 l) = 64 pairs x 256 ch. LDS 32KB.
__global__ __launch_bounds__(256, 3)
void k_main6(const float* __restrict__ ak, const float* __restrict__ al,
             const float* __restrict__ b1, const u16* __restrict__ w2i,
             const float* __restrict__ b2, const u16* __restrict__ w3i,
             const float* __restrict__ b3, float* __restrict__ part) {
    __shared__ u16 smem[64 * 256];  // 32 KB: h1, then h2 in-place
    const int tid = threadIdx.x;
    const int lc = blockIdx.x, kc = blockIdx.y, b = blockIdx.z;
    const int k0 = kc * 8, l0 = lc * 8;

    // ---- stage h1 = relu(ak[k] + al[l] + b1) -> bf16 LDS [pair][ch], swizzled ----
#pragma unroll
    for (int it = 0; it < 8; ++it) {
        int chunk = it * 256 + tid;
        int row = chunk >> 5;
        int cc = chunk & 31;
        int ki = k0 + (row >> 3); if (ki > 195) ki = 195;
        int li = l0 + (row & 7);  if (li > 195) li = 195;
        const float* akp = ak + ((b * kHW + ki) << 8) + (cc << 3);
        const float* alp = al + ((b * kHW + li) << 8) + (cc << 3);
        const float* b1p = b1 + (cc << 3);
        f32x4 k0v = *(const f32x4*)akp;
        f32x4 k1v = *(const f32x4*)(akp + 4);
        f32x4 l0v = *(const f32x4*)alp;
        f32x4 l1v = *(const f32x4*)(alp + 4);
        f32x4 c0v = *(const f32x4*)b1p;
        f32x4 c1v = *(const f32x4*)(b1p + 4);
        u16x8 v;
#pragma unroll
        for (int j = 0; j < 4; ++j) {
            v[j]     = f2bfu(fmaxf(k0v[j] + l0v[j] + c0v[j], 0.f));
            v[4 + j] = f2bfu(fmaxf(k1v[j] + l1v[j] + c1v[j], 0.f));
        }
        int byte = (row << 9) + (cc << 4);
        byte ^= (row & 7) << 4;
        *(u16x8*)((char*)smem + byte) = v;
    }
    __syncthreads();

    const int lane = tid & 63;
    const int wn = tid >> 6;   // wave = ch quarter 0..3
    const int l15 = lane & 15;
    const int kg = lane >> 4;  // 0..3

    f32x4 acc[4][4];  // [fn ch-frag][fm pair-frag], reused for both GEMMs

    // interleaved weight index: ((kk*4+kg)*256 + ch) * 8, ch = wn*64 + fn*16 + l15
    const int wbase = (wn * 64 + l15) << 3;  // + (fn*16)<<3 + ((kk*4+kg)<<11)

    // ---- GEMM1: h2^T = w2 x h1^T ----
#pragma unroll
    for (int fn = 0; fn < 4; ++fn)
#pragma unroll
        for (int fm = 0; fm < 4; ++fm) acc[fn][fm] = f32x4{0.f, 0.f, 0.f, 0.f};
    for (int kk = 0; kk < 8; ++kk) {
        int kb = kk * 32 + kg * 8;
        bf16x8 hb[4];
#pragma unroll
        for (int fm = 0; fm < 4; ++fm) {
            int row = fm * 16 + l15;
            int byte = (row << 9) + (kb << 1);
            byte ^= (row & 7) << 4;
            hb[fm] = __builtin_bit_cast(bf16x8, *(const u16x8*)((const char*)smem + byte));
        }
        const u16* wp = w2i + ((((kk << 2) + kg) << 11) + wbase);
#pragma unroll
        for (int fn = 0; fn < 4; ++fn) {
            bf16x8 aw = __builtin_bit_cast(bf16x8, *(const u16x8*)(wp + (fn << 7)));
#pragma unroll
            for (int fm = 0; fm < 4; ++fm)
                acc[fn][fm] = __builtin_amdgcn_mfma_f32_16x16x32_bf16(aw, hb[fm], acc[fn][fm], 0, 0, 0);
        }
    }
    __syncthreads();

    // ---- epilogue: h2 = relu(D1 + b2) -> bf16 LDS, packed 8B writes ----
#pragma unroll
    for (int fn = 0; fn < 4; ++fn) {
        f32x4 b2v = *(const f32x4*)(b2 + wn * 64 + fn * 16 + kg * 4);
#pragma unroll
        for (int fm = 0; fm < 4; ++fm) {
            int prow = fm * 16 + l15;
            u16x4 pv;
#pragma unroll
            for (int r = 0; r < 4; ++r)
                pv[r] = f2bfu(fmaxf(acc[fn][fm][r] + b2v[r], 0.f));
            int byte = (prow << 9) + ((wn * 64 + fn * 16 + kg * 4) << 1);
            byte ^= (prow & 7) << 4;
            *(u16x4*)((char*)smem + byte) = pv;
        }
    }
    __syncthreads();

    // ---- GEMM2: h3^T = w3 x h2^T ----
#pragma unroll
    for (int fn = 0; fn < 4; ++fn)
#pragma unroll
        for (int fm = 0; fm < 4; ++fm) acc[fn][fm] = f32x4{0.f, 0.f, 0.f, 0.f};
    for (int kk = 0; kk < 8; ++kk) {
        int kb = kk * 32 + kg * 8;
        bf16x8 hb[4];
#pragma unroll
        for (int fm = 0; fm < 4; ++fm) {
            int row = fm * 16 + l15;
            int byte = (row << 9) + (kb << 1);
            byte ^= (row & 7) << 4;
            hb[fm] = __builtin_bit_cast(bf16x8, *(const u16x8*)((const char*)smem + byte));
        }
        const u16* wp = w3i + ((((kk << 2) + kg) << 11) + wbase);
#pragma unroll
        for (int fn = 0; fn < 4; ++fn) {
            bf16x8 aw = __builtin_bit_cast(bf16x8, *(const u16x8*)(wp + (fn << 7)));
#pragma unroll
            for (int fm = 0; fm < 4; ++fm)
                acc[fn][fm] = __builtin_amdgcn_mfma_f32_16x16x32_bf16(aw, hb[fm], acc[fn][fm], 0, 0, 0);
        }
    }

    // ---- masked col-sum + wave reduce + direct store to part ----
    float s[4][4] = {};
#pragma unroll
    for (int fm = 0; fm < 4; ++fm) {
        int pr = fm * 16 + l15;
        int ki = k0 + (pr >> 3);
        int li = l0 + (pr & 7);
        float vm = (ki < kHW && li < kHW) ? 1.f : 0.f;
#pragma unroll
        for (int fn = 0; fn < 4; ++fn) {
            f32x4 b3v = *(const f32x4*)(b3 + wn * 64 + fn * 16 + kg * 4);
#pragma unroll
            for (int r = 0; r < 4; ++r)
                s[fn][r] += vm * fmaxf(acc[fn][fm][r] + b3v[r], 0.f);
        }
    }
#pragma unroll
    for (int fn = 0; fn < 4; ++fn)
#pragma unroll
        for (int r = 0; r < 4; ++r) {
            s[fn][r] += __shfl_xor(s[fn][r], 1);
            s[fn][r] += __shfl_xor(s[fn][r], 2);
            s[fn][r] += __shfl_xor(s[fn][r], 4);
            s[fn][r] += __shfl_xor(s[fn][r], 8);
        }
    if (l15 == 0) {
        int chunkid = (b * kKC + kc) * kLC + lc;
        float* pp = part + chunkid * 256 + wn * 64 + kg * 4;
#pragma unroll
        for (int fn = 0; fn < 4; ++fn)
            *(f32x4*)(pp + fn * 16) = f32x4{s[fn][0], s[fn][1], s[fn][2], s[fn][3]};
    }
}

// ---------------- final reduce over 625 chunks per batch ----------------
__global__ __launch_bounds__(1024)
void k_reduce(const float* __restrict__ part, float* __restrict__ out) {
    __shared__ float red[4][256];
    int b = blockIdx.x;
    int c = threadIdx.x & 255;
    int stripe = threadIdx.x >> 8;
    const float* p = part + (b * kChunks) * 256 + c;
    float s = 0.f;
    for (int j = stripe; j < kChunks; j += 4) s += p[j * 256];
    red[stripe][c] = s;
    __syncthreads();
    if (threadIdx.x < 256)
        out[b * 256 + threadIdx.x] = red[0][threadIdx.x] + red[1][threadIdx.x] +
                                     red[2][threadIdx.x] + red[3][threadIdx.x];
}

extern "C" void kernel_launch(void* const* d_in, const int* in_sizes, int n_in,
                              void* d_out, int out_size, void* d_ws, size_t ws_size,
                              hipStream_t stream) {
    const float* im = (const float*)d_in[0];
    const float* pw = (const float*)d_in[3];
    const float* pb = (const float*)d_in[4];
    const float* w1 = (const float*)d_in[5];
    const float* b1 = (const float*)d_in[6];
    const float* w2 = (const float*)d_in[7];
    const float* b2 = (const float*)d_in[8];
    const float* w3 = (const float*)d_in[9];
    const float* b3 = (const float*)d_in[10];
    float* out = (float*)d_out;

    float* al  = (float*)d_ws;            // 8*196*256
    float* ak  = al + 8 * 196 * 256;
    float* pwT = ak + 8 * 196 * 256;      // [512][256]
    u16* w2i = (u16*)(pwT + 512 * 256);   // [8kk][4kg][256ch][8k] bf16
    u16* w3i = w2i + 256 * 256;
    float* part = (float*)(w3i + 256 * 256);  // [8*625][256] = 5.12 MB

    hipLaunchKernelGGL(k_tr_f32, dim3(8, 4), dim3(256), 0, stream, pw, pwT, 256, 512);
    hipLaunchKernelGGL(k_wint, dim3(256), dim3(256), 0, stream, w2, w2i);
    hipLaunchKernelGGL(k_wint, dim3(256), dim3(256), 0, stream, w3, w3i);
    hipLaunchKernelGGL(k_xa, dim3(25, 8), dim3(512), 0, stream, im, pwT, pb, w1, al, ak);
    hipLaunchKernelGGL(k_main6, dim3(kLC, kKC, 8), dim3(256), 0, stream,
                       ak, al, b1, w2i, b2, w3i, b3, part);
    hipLaunchKernelGGL(k_reduce, dim3(8), dim3(1024), 0, stream, part, out);
}